// Round 4
// baseline (79.103 us; speedup 1.0000x reference)
//
#include <hip/hip_runtime.h>

#define NB 16
#define NL 64
#define ND 256
#define NU 500
#define NV 10000
#define MINWL 4
#define MAXWL 10
#define NWL 7
#define ITEMP 10.0f                 // 1/TEMP
#define L2I 14.4269504088896f       // 10 * log2(e)
#define KA  57.7078016355584f       // 4.0 * L2I  (fixed anchor * 10 * log2e)
#define CE  4.5399929762484854e-05f // exp(-10): per-k weight chain factor
#define NT 512

// ================= kernel 0: stable counting sort of vocab by len =================
__global__ __launch_bounds__(512) void k_sort(const int* __restrict__ vlen,
                                              int* __restrict__ origv,
                                              int* __restrict__ bases) {
    __shared__ unsigned long long sA[512], sB[512];
    __shared__ int base_s[8];
    int t = threadIdx.x;
    const int CH = (NV + 511) / 512;  // 20
    int lo = t * CH, hi = min(lo + CH, NV);
    int h[7] = {0, 0, 0, 0, 0, 0, 0};
    for (int v = lo; v < hi; ++v) h[vlen[v] - MINWL]++;
    unsigned long long a = (unsigned long long)h[0] | ((unsigned long long)h[1] << 16) |
                           ((unsigned long long)h[2] << 32) | ((unsigned long long)h[3] << 48);
    unsigned long long bq = (unsigned long long)h[4] | ((unsigned long long)h[5] << 16) |
                            ((unsigned long long)h[6] << 32);
    sA[t] = a; sB[t] = bq;
    __syncthreads();
    for (int o = 1; o < 512; o <<= 1) {  // inclusive Hillis-Steele scan
        unsigned long long va = 0, vb = 0;
        if (t >= o) { va = sA[t - o]; vb = sB[t - o]; }
        __syncthreads();
        sA[t] += va; sB[t] += vb;
        __syncthreads();
    }
    if (t == 0) {
        unsigned long long A = sA[511], Bq = sB[511];
        int tot[7] = {(int)(A & 0xFFFF), (int)((A >> 16) & 0xFFFF), (int)((A >> 32) & 0xFFFF),
                      (int)((A >> 48) & 0xFFFF), (int)(Bq & 0xFFFF), (int)((Bq >> 16) & 0xFFFF),
                      (int)((Bq >> 32) & 0xFFFF)};
        int run = 0;
        for (int l = 0; l < 7; ++l) { base_s[l] = run; run += tot[l]; }
        base_s[7] = run;  // == NV
        for (int i = 0; i < 8; ++i) bases[i] = base_s[i];
    }
    __syncthreads();
    unsigned long long eA = sA[t] - a, eB = sB[t] - bq;  // exclusive prefix
    int pos[7];
#pragma unroll
    for (int l = 0; l < 4; ++l) pos[l] = base_s[l] + (int)((eA >> (16 * l)) & 0xFFFF);
#pragma unroll
    for (int l = 4; l < 7; ++l) pos[l] = base_s[l] + (int)((eB >> (16 * (l - 4))) & 0xFFFF);
    for (int v = lo; v < hi; ++v) {  // stable: ascending v within thread
        int l = vlen[v] - MINWL;
        origv[pos[l]++] = v;
    }
}

// ================= kernel 0b: gather seg rows into sorted SoA layout =================
__global__ __launch_bounds__(256) void k_gather(const int* __restrict__ origv,
                                                const int* __restrict__ seg,
                                                int* __restrict__ segT) {
    int i = blockIdx.x * 256 + threadIdx.x;
    if (i >= NV) return;
    int v = origv[i];
    const int2* sp = (const int2*)(seg + v * MAXWL);
#pragma unroll
    for (int jj = 0; jj < 5; ++jj) {
        int2 p = sp[jj];
        segT[(2 * jj) * NV + i] = p.x;
        segT[(2 * jj + 1) * NV + i] = p.y;
    }
}

// ================= kernel 1: sim = normalize(word) @ normalize(unit)^T =================
#define LT 32
#define UC 32
#define SSTR 260
#define SIM_LDS_BYTES ((2 * 32 * SSTR + 64) * 4)

__global__ __launch_bounds__(256) void k_sim(const float* __restrict__ word,
                                             const float* __restrict__ unit,
                                             float* __restrict__ sim) {
    extern __shared__ float lds[];
    float* wt = lds;                    // [32][SSTR]
    float* ut = lds + 32 * SSTR;        // [32][SSTR]
    float* scaleW = lds + 64 * SSTR;    // [32]
    float* scaleU = scaleW + 32;        // [32]
    int blk = blockIdx.x;  // b*32 + lt*16 + uc
    int uc = blk & 15, lt = (blk >> 4) & 1, b = blk >> 5;
    int l0 = lt * 32, u0 = uc * 32;
    int t = threadIdx.x;

#pragma unroll
    for (int i = 0; i < 32; ++i)
        wt[i * SSTR + t] = word[(b * NL + l0 + i) * ND + t];
#pragma unroll
    for (int i = 0; i < 32; ++i) {
        int u = u0 + i;
        ut[i * SSTR + t] = (u < NU) ? unit[u * ND + t] : 1.0f;
    }
    __syncthreads();
#pragma unroll
    for (int h = 0; h < 2; ++h) {  // 32 rows, 16 threads/row, two rounds
        int r = (t >> 4) + h * 16, p = t & 15;
        float sw = 0.f, su = 0.f;
#pragma unroll
        for (int c = 0; c < 16; ++c) {
            float x = wt[r * SSTR + p * 16 + c];
            float y = ut[r * SSTR + p * 16 + c];
            sw += x * x; su += y * y;
        }
#pragma unroll
        for (int o = 1; o < 16; o <<= 1) {
            sw += __shfl_xor(sw, o);
            su += __shfl_xor(su, o);
        }
        if (p == 0) { scaleW[r] = 1.0f / sqrtf(sw); scaleU[r] = 1.0f / sqrtf(su); }
    }
    __syncthreads();

    int lane = t & 15;   // unit pair: rows lane, lane+16
    int lp = t >> 4;     // 0..15 -> word rows lp*2, lp*2+1
    int l = lp * 2;
    const float4* w0p = (const float4*)(wt + l * SSTR);
    const float4* w1p = (const float4*)(wt + (l + 1) * SSTR);
    const float4* x0p = (const float4*)(ut + lane * SSTR);
    const float4* x1p = (const float4*)(ut + (lane + 16) * SSTR);
    float a00 = 0.f, a01 = 0.f, a10 = 0.f, a11 = 0.f;
#pragma unroll 8
    for (int dq = 0; dq < ND / 4; ++dq) {
        float4 w0 = w0p[dq], w1 = w1p[dq], x0 = x0p[dq], x1 = x1p[dq];
        a00 += w0.x * x0.x + w0.y * x0.y + w0.z * x0.z + w0.w * x0.w;
        a01 += w0.x * x1.x + w0.y * x1.y + w0.z * x1.z + w0.w * x1.w;
        a10 += w1.x * x0.x + w1.y * x0.y + w1.z * x0.z + w1.w * x0.w;
        a11 += w1.x * x1.x + w1.y * x1.y + w1.z * x1.z + w1.w * x1.w;
    }
    float sw0 = scaleW[l], sw1 = scaleW[l + 1];
    float su0 = scaleU[lane], su1 = scaleU[lane + 16];
    int gu0 = u0 + lane, gu1 = u0 + lane + 16;
    int base = (b * NL + l0 + l) * NU;
    if (gu0 < NU) { sim[base + gu0] = a00 * (sw0 * su0); sim[base + NU + gu0] = a10 * (sw1 * su0); }
    if (gu1 < NU) { sim[base + gu1] = a01 * (sw0 * su1); sim[base + NU + gu1] = a11 * (sw1 * su1); }
}

// ================= kernel 2: per-(b,s) soft-min over vocab (bucketed) =================
// Fixed anchor 4.0: w = exp((4-e)*10); anchor cancels in W/S so no rescales and
// S,W merge by PLAIN SUM. Exact min/argmin (smallest original v on exact ties ==
// jnp.argmin first-occurrence). DPP wave reduction: zero LDS traffic.

template <int CTRL, int RM, bool BC>
__device__ __forceinline__ void red_step(float& m, int& ix, float& S, float& W) {
    float tm = __int_as_float(__builtin_amdgcn_update_dpp(
        __float_as_int(m), __float_as_int(m), CTRL, RM, 0xF, false));
    int ti = __builtin_amdgcn_update_dpp(ix, ix, CTRL, RM, 0xF, false);
    float tS = __int_as_float(__builtin_amdgcn_update_dpp(
        0, __float_as_int(S), CTRL, RM, 0xF, BC));
    float tW = __int_as_float(__builtin_amdgcn_update_dpp(
        0, __float_as_int(W), CTRL, RM, 0xF, BC));
    bool take = (tm < m) || (tm == m && ti < ix);
    ix = take ? ti : ix;
    m = take ? tm : m;
    S += tS;
    W += tW;
}

template <int L>
__device__ __forceinline__ void bucket_pass(int lo, int hi, int t, int wlmax,
                                            const int* __restrict__ segT,
                                            const int* __restrict__ origv,
                                            const float* __restrict__ dl,
                                            float* m, float* S, float* W, int* ix) {
    for (int i0 = lo; i0 < hi; i0 += NT) {
        int i = i0 + t;
        bool valid = i < hi;
        int ic = valid ? i : hi - 1;
        int ov = origv[ic];
        float d[MAXWL];
#pragma unroll
        for (int j = 0; j < L; ++j) {
            if (j < 4) {
                d[j] = dl[j * NU + segT[j * NV + ic]];
            } else {
                float g = dl[j * NU + segT[j * NV + ic]];
                d[j] = (j < wlmax) ? g : 0.0f;  // block-uniform branch
            }
        }
        d[0] = valid ? d[0] : 3.0e38f;  // poison: never captured (== m init), w==0
        float pj = ((d[0] + d[1]) + d[2]) + d[3];
        float ed[NWL], w[NWL];
#pragma unroll
        for (int k = 0; k < NWL; ++k) {
            if (4 + k < L)       { ed[k] = pj + (float)(L - 4 - k); pj += d[4 + k]; }
            else if (4 + k == L) { ed[k] = pj; }
            else                 { ed[k] = pj + (float)(4 + k - L); }  // pj == p_L
        }
#pragma unroll
        for (int k = 0; k < NWL; ++k) {
            if (4 + k <= L) w[k] = __builtin_amdgcn_exp2f(fmaf(ed[k], -L2I, KA));
            else            w[k] = w[k - 1] * CE;
        }
#pragma unroll
        for (int k = 0; k < NWL; ++k) {
            S[k] += w[k];
            W[k] = fmaf(ed[k], w[k], W[k]);
            bool lt = ed[k] < m[k];  // strict
            ix[k] = lt ? ov : ix[k];
            m[k] = lt ? ed[k] : m[k];
        }
    }
}

__global__ __launch_bounds__(NT, 4) void k_extract(const float* __restrict__ sim,
                                                   const int* __restrict__ segT,
                                                   const int* __restrict__ origv,
                                                   const int* __restrict__ bases,
                                                   float* __restrict__ dense,
                                                   int* __restrict__ mv) {
    int blk = blockIdx.x;  // b*64 + s
    int s = blk & (NL - 1), b = blk >> 6;
    int t = threadIdx.x;
    int wlmax = min(MAXWL, NL - s);
    if (wlmax < MINWL) {
        if (t < NL) dense[blk * NL + t] = 0.0f;
        return;
    }
    int kmax = wlmax - MINWL;  // block-uniform

    __shared__ float dl[MAXWL * NU];  // d = 1 - sim for rows s..s+wlmax-1
    for (int j = 0; j < wlmax; ++j)
        if (t < NU) dl[j * NU + t] = 1.0f - sim[(b * NL + s + j) * NU + t];
    __syncthreads();

    float m[NWL], S[NWL], W[NWL];
    int ix[NWL];
#pragma unroll
    for (int k = 0; k < NWL; ++k) { m[k] = 3.0e38f; S[k] = 0.f; W[k] = 0.f; ix[k] = 0; }

    bucket_pass<4>(bases[0], bases[1], t, wlmax, segT, origv, dl, m, S, W, ix);
    bucket_pass<5>(bases[1], bases[2], t, wlmax, segT, origv, dl, m, S, W, ix);
    bucket_pass<6>(bases[2], bases[3], t, wlmax, segT, origv, dl, m, S, W, ix);
    bucket_pass<7>(bases[3], bases[4], t, wlmax, segT, origv, dl, m, S, W, ix);
    bucket_pass<8>(bases[4], bases[5], t, wlmax, segT, origv, dl, m, S, W, ix);
    bucket_pass<9>(bases[5], bases[6], t, wlmax, segT, origv, dl, m, S, W, ix);
    bucket_pass<10>(bases[6], bases[7], t, wlmax, segT, origv, dl, m, S, W, ix);

    // wave reduction via DPP (canonical shr 1/2/4/8 + bcast15/31); result lane 63
#pragma unroll
    for (int k = 0; k < NWL; ++k) {
        red_step<0x111, 0xF, true>(m[k], ix[k], S[k], W[k]);
        red_step<0x112, 0xF, true>(m[k], ix[k], S[k], W[k]);
        red_step<0x114, 0xF, true>(m[k], ix[k], S[k], W[k]);
        red_step<0x118, 0xF, true>(m[k], ix[k], S[k], W[k]);
        red_step<0x142, 0xA, false>(m[k], ix[k], S[k], W[k]);
        red_step<0x143, 0xC, false>(m[k], ix[k], S[k], W[k]);
    }

    __shared__ float rm[8][NWL], rS[8][NWL], rW[8][NWL];
    __shared__ int rI[8][NWL];
    __shared__ float scoreRow[NWL];
    int wv = t >> 6;
    if ((t & 63) == 63) {
#pragma unroll
        for (int k = 0; k < NWL; ++k) {
            rm[wv][k] = m[k]; rS[wv][k] = S[k]; rW[wv][k] = W[k]; rI[wv][k] = ix[k];
        }
    }
    __syncthreads();
    if (t < NWL) {  // thread t == k; plain merges (fixed anchor)
        int k = t;
        float mm = rm[0][k], SS = rS[0][k], WW = rW[0][k];
        int II = rI[0][k];
#pragma unroll
        for (int w2 = 1; w2 < 8; ++w2) {
            float m2 = rm[w2][k];
            int i2 = rI[w2][k];
            bool take = (m2 < mm) || (m2 == mm && i2 < II);
            II = take ? i2 : II;
            mm = take ? m2 : mm;
            SS += rS[w2][k];
            WW += rW[w2][k];
        }
        if (k <= kmax) {
            float med = WW / SS;  // matched_ed (anchor cancels)
            float wl = (float)(MINWL + k);
            float z = 1.0f - 2.0f * (med / wl);
            float cel = (z > 0.f) ? z : (__expf(z) - 1.0f);  // celu
            scoreRow[k] = 0.5f * (cel + 1.0f) * wl;
            mv[(b * NL + s) * NWL + k] = II;
        }
    }
    __syncthreads();
    if (t < NL) {  // dense row: e = t -> k = e-s-3
        int k = t - s - (MINWL - 1);
        float val = (k >= 0 && k <= kmax) ? scoreRow[k] : 0.0f;
        dense[blk * NL + t] = val;
    }
}

// ================= kernel 3: per-b soft-max over spans + outputs =================
__global__ __launch_bounds__(256) void k_final(const float* __restrict__ dense,
                                               const int* __restrict__ mv,
                                               float* __restrict__ out) {
    int b = blockIdx.x, t = threadIdx.x;
    float m = -3.0e38f, S = 0.f, W = 0.f;
    int ix = 0;
    for (int i = t; i < NL * NL; i += 256) {
        float x = dense[b * NL * NL + i];
        if (x > m) {
            float f = __expf((m - x) * ITEMP);
            S = S * f + 1.0f;
            W = W * f + x;
            m = x;
            ix = i;
        } else {
            float w = __expf((x - m) * ITEMP);
            S += w;
            W += x * w;
        }
    }
#pragma unroll
    for (int o = 32; o >= 1; o >>= 1) {
        float m2 = __shfl_down(m, o);
        float S2 = __shfl_down(S, o);
        float W2 = __shfl_down(W, o);
        int i2 = __shfl_down(ix, o);
        float mx = fmaxf(m, m2);
        float fa = __expf((m - mx) * ITEMP);
        float fb = __expf((m2 - mx) * ITEMP);
        S = S * fa + S2 * fb;
        W = W * fa + W2 * fb;
        ix = (m2 > m || (m2 == m && i2 < ix)) ? i2 : ix;
        m = mx;
    }
    __shared__ float rm[4], rS[4], rW[4];
    __shared__ int rI[4];
    if ((t & 63) == 0) { int wv = t >> 6; rm[wv] = m; rS[wv] = S; rW[wv] = W; rI[wv] = ix; }
    __syncthreads();
    if (t == 0) {
        float mm = rm[0], SS = rS[0], WW = rW[0];
        int II = rI[0];
#pragma unroll
        for (int wv = 1; wv < 4; ++wv) {
            float m2 = rm[wv], S2 = rS[wv], W2 = rW[wv];
            int i2 = rI[wv];
            float mx = fmaxf(mm, m2);
            float fa = __expf((mm - mx) * ITEMP);
            float fb = __expf((m2 - mx) * ITEMP);
            SS = SS * fa + S2 * fb;
            WW = WW * fa + W2 * fb;
            II = (m2 > mm || (m2 == mm && i2 < II)) ? i2 : II;
            mm = mx;
        }
        float best = WW / SS;
        int st = II >> 6, en = II & (NL - 1);
        int ks = en - st + 1 - MINWL;
        ks = ks < 0 ? 0 : (ks > NWL - 1 ? NWL - 1 : ks);
        int bv = mv[(b * NL + st) * NWL + ks];
        out[b] = (float)st;
        out[NB + b] = (float)en;
        out[2 * NB + b] = best;
        out[3 * NB + b] = (float)bv;
    }
}

extern "C" void kernel_launch(void* const* d_in, const int* in_sizes, int n_in,
                              void* d_out, int out_size, void* d_ws, size_t ws_size,
                              hipStream_t stream) {
    const float* word = (const float*)d_in[0];   // (B,L,D) f32
    const float* unit = (const float*)d_in[1];   // (U,D) f32
    const int* seg = (const int*)d_in[2];        // (V,MAXWL) i32
    const int* vlen = (const int*)d_in[3];       // (V,) i32
    float* out = (float*)d_out;                  // [start|end|score|vocab|dense]
    char* ws = (char*)d_ws;
    float* sim = (float*)ws;                     // 2,048,000 B
    int* mv = (int*)(ws + 2048000);              // 28,672 B
    int* origv = (int*)(ws + 2076672);           // 40,000 B
    int* segT = (int*)(ws + 2116672);            // 400,000 B
    int* bases = (int*)(ws + 2516672);           // 32 B
    float* dense = out + 4 * NB;

    hipFuncSetAttribute((const void*)k_sim,
                        hipFuncAttributeMaxDynamicSharedMemorySize, SIM_LDS_BYTES);

    k_sort<<<1, 512, 0, stream>>>(vlen, origv, bases);
    k_gather<<<(NV + 255) / 256, 256, 0, stream>>>(origv, seg, segT);
    k_sim<<<NB * 2 * 16, 256, SIM_LDS_BYTES, stream>>>(word, unit, sim);
    k_extract<<<NB * NL, NT, 0, stream>>>(sim, segT, origv, bases, dense, mv);
    k_final<<<NB, 256, 0, stream>>>(dense, mv, out);
}

// Round 5
// 72.063 us; speedup vs baseline: 1.0977x; 1.0977x over previous
//
#include <hip/hip_runtime.h>

#define NB 16
#define NL 64
#define ND 256
#define NU 500
#define NV 10000
#define MINWL 4
#define MAXWL 10
#define NWL 7
#define ITEMP 10.0f                 // 1/TEMP
#define L2I 14.4269504088896f       // 10 * log2(e)
#define NT 512

// ================= kernel 0: stable counting sort of vocab by len =================
// Scratch-free (packed u64 counters, rule #20), shfl-based scan, 2 barriers.
__global__ __launch_bounds__(512) void k_sort(const int* __restrict__ vlen,
                                              int* __restrict__ origv,
                                              int* __restrict__ bases) {
    int t = threadIdx.x;
    const int CH = 20;  // 512*20 >= NV
    int lo = t * CH, hi = min(lo + CH, NV);
    // packed per-thread histogram: hA fields l=0..3, hB fields l=4..6 (16b each)
    unsigned long long hA = 0, hB = 0;
    for (int v = lo; v < hi; ++v) {
        int l = vlen[v] - MINWL;               // 0..6
        int sh = (l & 3) * 16;                  // l&3 == l-4 for l>=4
        unsigned long long inc = 1ULL << sh;
        bool isA = l < 4;
        hA += isA ? inc : 0ULL;
        hB += isA ? 0ULL : inc;
    }
    // wave-inclusive scan
    int lane = t & 63, wv = t >> 6;
    unsigned long long iA = hA, iB = hB;
#pragma unroll
    for (int o = 1; o < 64; o <<= 1) {
        unsigned long long a2 = (unsigned long long)__shfl_up((long long)iA, o);
        unsigned long long b2 = (unsigned long long)__shfl_up((long long)iB, o);
        if (lane >= o) { iA += a2; iB += b2; }
    }
    __shared__ unsigned long long wA[8], wB[8];
    __shared__ int base_s[8];
    if (lane == 63) { wA[wv] = iA; wB[wv] = iB; }
    __syncthreads();
    unsigned long long pA = 0, pB = 0, tA = 0, tB = 0;
#pragma unroll
    for (int w2 = 0; w2 < 8; ++w2) {
        if (w2 < wv) { pA += wA[w2]; pB += wB[w2]; }
        tA += wA[w2]; tB += wB[w2];
    }
    unsigned long long eA = pA + iA - hA, eB = pB + iB - hB;  // exclusive prefix
    if (t == 0) {
        int tot[7] = {(int)(tA & 0xFFFF), (int)((tA >> 16) & 0xFFFF),
                      (int)((tA >> 32) & 0xFFFF), (int)((tA >> 48) & 0xFFFF),
                      (int)(tB & 0xFFFF), (int)((tB >> 16) & 0xFFFF),
                      (int)((tB >> 32) & 0xFFFF)};
        int run = 0;
        for (int l = 0; l < 7; ++l) { base_s[l] = run; bases[l] = run; run += tot[l]; }
        base_s[7] = run; bases[7] = run;
    }
    __syncthreads();
    // packed write positions: field l = base_s[l] + eprefix[l]  (all <= 10000, fits u16)
    unsigned long long qA = eA + ((unsigned long long)base_s[0] |
                                  ((unsigned long long)base_s[1] << 16) |
                                  ((unsigned long long)base_s[2] << 32) |
                                  ((unsigned long long)base_s[3] << 48));
    unsigned long long qB = eB + ((unsigned long long)base_s[4] |
                                  ((unsigned long long)base_s[5] << 16) |
                                  ((unsigned long long)base_s[6] << 32));
    for (int v = lo; v < hi; ++v) {  // stable: ascending v within thread
        int l = vlen[v] - MINWL;
        int sh = (l & 3) * 16;
        bool isA = l < 4;
        unsigned long long cur = isA ? qA : qB;
        int pos = (int)((cur >> sh) & 0xFFFF);
        origv[pos] = v;
        unsigned long long inc = 1ULL << sh;
        qA += isA ? inc : 0ULL;
        qB += isA ? 0ULL : inc;
    }
}

// ================= kernel 0b: gather seg rows into sorted SoA layout =================
__global__ __launch_bounds__(256) void k_gather(const int* __restrict__ origv,
                                                const int* __restrict__ seg,
                                                int* __restrict__ segT) {
    int i = blockIdx.x * 256 + threadIdx.x;
    if (i >= NV) return;
    int v = origv[i];
    const int2* sp = (const int2*)(seg + v * MAXWL);
#pragma unroll
    for (int jj = 0; jj < 5; ++jj) {
        int2 p = sp[jj];
        segT[(2 * jj) * NV + i] = p.x;
        segT[(2 * jj + 1) * NV + i] = p.y;
    }
}

// ================= kernel 1: sim = normalize(word) @ normalize(unit)^T =================
#define SSTR 260
#define SIM_LDS_BYTES ((2 * 32 * SSTR + 64) * 4)

__global__ __launch_bounds__(256) void k_sim(const float* __restrict__ word,
                                             const float* __restrict__ unit,
                                             float* __restrict__ sim) {
    extern __shared__ float lds[];
    float* wt = lds;                    // [32][SSTR]
    float* ut = lds + 32 * SSTR;        // [32][SSTR]
    float* scaleW = lds + 64 * SSTR;    // [32]
    float* scaleU = scaleW + 32;        // [32]
    int blk = blockIdx.x;  // b*32 + lt*16 + uc
    int uc = blk & 15, lt = (blk >> 4) & 1, b = blk >> 5;
    int l0 = lt * 32, u0 = uc * 32;
    int t = threadIdx.x;

#pragma unroll
    for (int i = 0; i < 32; ++i)
        wt[i * SSTR + t] = word[(b * NL + l0 + i) * ND + t];
#pragma unroll
    for (int i = 0; i < 32; ++i) {
        int u = u0 + i;
        ut[i * SSTR + t] = (u < NU) ? unit[u * ND + t] : 1.0f;
    }
    __syncthreads();
#pragma unroll
    for (int h = 0; h < 2; ++h) {
        int r = (t >> 4) + h * 16, p = t & 15;
        float sw = 0.f, su = 0.f;
#pragma unroll
        for (int c = 0; c < 16; ++c) {
            float x = wt[r * SSTR + p * 16 + c];
            float y = ut[r * SSTR + p * 16 + c];
            sw += x * x; su += y * y;
        }
#pragma unroll
        for (int o = 1; o < 16; o <<= 1) {
            sw += __shfl_xor(sw, o);
            su += __shfl_xor(su, o);
        }
        if (p == 0) { scaleW[r] = 1.0f / sqrtf(sw); scaleU[r] = 1.0f / sqrtf(su); }
    }
    __syncthreads();

    int lane = t & 15;
    int lp = t >> 4;
    int l = lp * 2;
    const float4* w0p = (const float4*)(wt + l * SSTR);
    const float4* w1p = (const float4*)(wt + (l + 1) * SSTR);
    const float4* x0p = (const float4*)(ut + lane * SSTR);
    const float4* x1p = (const float4*)(ut + (lane + 16) * SSTR);
    float a00 = 0.f, a01 = 0.f, a10 = 0.f, a11 = 0.f;
#pragma unroll 8
    for (int dq = 0; dq < ND / 4; ++dq) {
        float4 w0 = w0p[dq], w1 = w1p[dq], x0 = x0p[dq], x1 = x1p[dq];
        a00 += w0.x * x0.x + w0.y * x0.y + w0.z * x0.z + w0.w * x0.w;
        a01 += w0.x * x1.x + w0.y * x1.y + w0.z * x1.z + w0.w * x1.w;
        a10 += w1.x * x0.x + w1.y * x0.y + w1.z * x0.z + w1.w * x0.w;
        a11 += w1.x * x1.x + w1.y * x1.y + w1.z * x1.z + w1.w * x1.w;
    }
    float sw0 = scaleW[l], sw1 = scaleW[l + 1];
    float su0 = scaleU[lane], su1 = scaleU[lane + 16];
    int gu0 = u0 + lane, gu1 = u0 + lane + 16;
    int base = (b * NL + l0 + l) * NU;
    if (gu0 < NU) { sim[base + gu0] = a00 * (sw0 * su0); sim[base + NU + gu0] = a10 * (sw1 * su0); }
    if (gu1 < NU) { sim[base + gu1] = a01 * (sw0 * su1); sim[base + NU + gu1] = a11 * (sw1 * su1); }
}

// ================= kernel 2: per-(b,s) soft-min over vocab (bucket-factored) =================
// Per-k anchor wl_k=4+k makes the weight exponent (4+k)-ed_k = L-pref(L) identical
// for ALL k >= L-4: one exp2 serves them all; per-bucket scalars {Sb,Wb,mb,ixb}
// expand at bucket end: S_k += Sb; W_k += Wb + c_k*Sb; cand = mb + (float)c_k
// (bit-exact same op as reference's q + (float)|wl-len|). k = L-5 (penalty 1,
// e^-10 relative) tracked separately; k <= L-6 dropped (e^-20 relative, ~1e-9).

template <int CTRL, int RM, bool BC>
__device__ __forceinline__ void red_step(float& m, int& ix, float& S, float& W) {
    float tm = __int_as_float(__builtin_amdgcn_update_dpp(
        __float_as_int(m), __float_as_int(m), CTRL, RM, 0xF, false));
    int ti = __builtin_amdgcn_update_dpp(ix, ix, CTRL, RM, 0xF, false);
    float tS = __int_as_float(__builtin_amdgcn_update_dpp(
        0, __float_as_int(S), CTRL, RM, 0xF, BC));
    float tW = __int_as_float(__builtin_amdgcn_update_dpp(
        0, __float_as_int(W), CTRL, RM, 0xF, BC));
    bool take = (tm < m) || (tm == m && ti < ix);
    ix = take ? ti : ix;
    m = take ? tm : m;
    S += tS;
    W += tW;
}

template <int L>
__device__ __forceinline__ void bucket_pass(int lo, int hi, int t, int wlmax, int kmax,
                                            const int* __restrict__ segT,
                                            const float* __restrict__ dl,
                                            float* m, float* S, float* W, int* ix) {
    if (L - 5 > kmax) return;  // bucket serves no k for this block
    float Sb = 0.f, Wb = 0.f, Sm = 0.f, Wm = 0.f;
    float mb = 3.0e38f, mm = 3.0e38f;
    int ixb = 0, ixm = 0;
    for (int i0 = lo; i0 < hi; i0 += NT) {
        int i = i0 + t;
        bool valid = i < hi;
        int ic = valid ? i : hi - 1;
        float d[L];
#pragma unroll
        for (int j = 0; j < L; ++j) {
            float g = dl[j * NU + segT[j * NV + ic]];
            d[j] = (j < 4) ? g : ((j < wlmax) ? g : 0.0f);
        }
        d[0] = valid ? d[0] : 3.0e38f;  // poison: w underflows to 0, min never taken
        float q = ((d[0] + d[1]) + d[2]) + d[3];
        float pm = q;  // pref(L-1) for L>=5 (set in loop below)
#pragma unroll
        for (int j = 4; j < L; ++j) {
            if (j == L - 1) pm = q;
            q += d[j];
        }
        // k >= L-4 family: shared weight, anchor cancels the penalty exactly
        float wb = __builtin_amdgcn_exp2f(fmaf(q, -L2I, (float)L * L2I));
        Sb += wb;
        Wb = fmaf(q, wb, Wb);
        bool ltb = q < mb;
        ixb = ltb ? i : ixb;
        mb = ltb ? q : mb;
        if constexpr (L >= 5) {  // k = L-5: ed = pref(L-1) + 1, anchor L-1
            float edm = pm + 1.0f;
            float wm_ = __builtin_amdgcn_exp2f(fmaf(edm, -L2I, (float)(L - 1) * L2I));
            Sm += wm_;
            Wm = fmaf(edm, wm_, Wm);
            bool ltm = edm < mm;
            ixm = ltm ? i : ixm;
            mm = ltm ? edm : mm;
        }
    }
    // bucket-end expansion into per-k accumulators
#pragma unroll
    for (int k = 0; k < NWL; ++k) {
        if (k >= L - 4) {
            if (k <= kmax) {
                float c = (float)(k + 4 - L);
                S[k] += Sb;
                W[k] += fmaf(c, Sb, Wb);
                float cand = mb + c;  // bit-exact: same op as reference
                bool take = (cand < m[k]) || (cand == m[k] && ixb < ix[k]);
                ix[k] = take ? ixb : ix[k];
                m[k] = take ? cand : m[k];
            }
        }
        if constexpr (L >= 5) {
            if (k == L - 5 && k <= kmax) {
                S[k] += Sm;
                W[k] += Wm;
                bool take = (mm < m[k]) || (mm == m[k] && ixm < ix[k]);
                ix[k] = take ? ixm : ix[k];
                m[k] = take ? mm : m[k];
            }
        }
    }
}

__global__ __launch_bounds__(NT, 4) void k_extract(const float* __restrict__ sim,
                                                   const int* __restrict__ segT,
                                                   const int* __restrict__ origv,
                                                   const int* __restrict__ basesG,
                                                   float* __restrict__ dense,
                                                   int* __restrict__ mv) {
    int blk = blockIdx.x;  // b*64 + s
    int s = blk & (NL - 1), b = blk >> 6;
    int t = threadIdx.x;
    int wlmax = min(MAXWL, NL - s);
    if (wlmax < MINWL) {
        if (t < NL) dense[blk * NL + t] = 0.0f;
        return;
    }
    int kmax = wlmax - MINWL;  // block-uniform

    int bs[8];
#pragma unroll
    for (int i = 0; i < 8; ++i) bs[i] = __builtin_amdgcn_readfirstlane(basesG[i]);

    __shared__ float dl[MAXWL * NU];  // d = 1 - sim rows s..s+wlmax-1 (20KB)
    for (int j = 0; j < wlmax; ++j)
        if (t < NU) dl[j * NU + t] = 1.0f - sim[(b * NL + s + j) * NU + t];
    __syncthreads();

    float m[NWL], S[NWL], W[NWL];
    int ix[NWL];
#pragma unroll
    for (int k = 0; k < NWL; ++k) { m[k] = 3.0e38f; S[k] = 0.f; W[k] = 0.f; ix[k] = 0; }

    bucket_pass<4>(bs[0], bs[1], t, wlmax, kmax, segT, dl, m, S, W, ix);
    bucket_pass<5>(bs[1], bs[2], t, wlmax, kmax, segT, dl, m, S, W, ix);
    bucket_pass<6>(bs[2], bs[3], t, wlmax, kmax, segT, dl, m, S, W, ix);
    bucket_pass<7>(bs[3], bs[4], t, wlmax, kmax, segT, dl, m, S, W, ix);
    bucket_pass<8>(bs[4], bs[5], t, wlmax, kmax, segT, dl, m, S, W, ix);
    bucket_pass<9>(bs[5], bs[6], t, wlmax, kmax, segT, dl, m, S, W, ix);
    bucket_pass<10>(bs[6], bs[7], t, wlmax, kmax, segT, dl, m, S, W, ix);

    // wave reduction via DPP; result in lane 63 of each wave
#pragma unroll
    for (int k = 0; k < NWL; ++k) {
        red_step<0x111, 0xF, true>(m[k], ix[k], S[k], W[k]);
        red_step<0x112, 0xF, true>(m[k], ix[k], S[k], W[k]);
        red_step<0x114, 0xF, true>(m[k], ix[k], S[k], W[k]);
        red_step<0x118, 0xF, true>(m[k], ix[k], S[k], W[k]);
        red_step<0x142, 0xA, false>(m[k], ix[k], S[k], W[k]);
        red_step<0x143, 0xC, false>(m[k], ix[k], S[k], W[k]);
    }

    // cross-wave reduce: alias scratch into dl (all gathers done)
    __syncthreads();
    float* rm = dl;                    // [8][NWL]
    float* rS = dl + 64;
    float* rW = dl + 128;
    int* rI = (int*)(dl + 192);
    float* scoreRow = dl + 256;
    int wv = t >> 6;
    if ((t & 63) == 63) {
#pragma unroll
        for (int k = 0; k < NWL; ++k) {
            rm[wv * NWL + k] = m[k]; rS[wv * NWL + k] = S[k];
            rW[wv * NWL + k] = W[k]; rI[wv * NWL + k] = ix[k];
        }
    }
    __syncthreads();
    if (t < NWL) {  // thread t == k; plain sums (consistent per-k anchor)
        int k = t;
        float mm = rm[k], SS = rS[k], WW = rW[k];
        int II = rI[k];
#pragma unroll
        for (int w2 = 1; w2 < 8; ++w2) {
            float m2 = rm[w2 * NWL + k];
            int i2 = rI[w2 * NWL + k];
            bool take = (m2 < mm) || (m2 == mm && i2 < II);
            II = take ? i2 : II;
            mm = take ? m2 : mm;
            SS += rS[w2 * NWL + k];
            WW += rW[w2 * NWL + k];
        }
        if (k <= kmax) {
            float med = WW / SS;  // matched_ed (anchor cancels)
            float wl = (float)(MINWL + k);
            float z = 1.0f - 2.0f * (med / wl);
            float cel = (z > 0.f) ? z : (__expf(z) - 1.0f);  // celu
            scoreRow[k] = 0.5f * (cel + 1.0f) * wl;
            mv[(b * NL + s) * NWL + k] = origv[II];  // sorted idx -> original v
        }
    }
    __syncthreads();
    if (t < NL) {  // dense row: e = t -> k = e-s-3
        int k = t - s - (MINWL - 1);
        float val = (k >= 0 && k <= kmax) ? scoreRow[k] : 0.0f;
        dense[blk * NL + t] = val;
    }
}

// ================= kernel 3: per-b soft-max over spans + outputs =================
__global__ __launch_bounds__(256) void k_final(const float* __restrict__ dense,
                                               const int* __restrict__ mv,
                                               float* __restrict__ out) {
    int b = blockIdx.x, t = threadIdx.x;
    float m = -3.0e38f, S = 0.f, W = 0.f;
    int ix = 0;
    for (int i = t; i < NL * NL; i += 256) {
        float x = dense[b * NL * NL + i];
        if (x > m) {
            float f = __expf((m - x) * ITEMP);
            S = S * f + 1.0f;
            W = W * f + x;
            m = x;
            ix = i;
        } else {
            float w = __expf((x - m) * ITEMP);
            S += w;
            W += x * w;
        }
    }
#pragma unroll
    for (int o = 32; o >= 1; o >>= 1) {
        float m2 = __shfl_down(m, o);
        float S2 = __shfl_down(S, o);
        float W2 = __shfl_down(W, o);
        int i2 = __shfl_down(ix, o);
        float mx = fmaxf(m, m2);
        float fa = __expf((m - mx) * ITEMP);
        float fb = __expf((m2 - mx) * ITEMP);
        S = S * fa + S2 * fb;
        W = W * fa + W2 * fb;
        ix = (m2 > m || (m2 == m && i2 < ix)) ? i2 : ix;
        m = mx;
    }
    __shared__ float rm[4], rS[4], rW[4];
    __shared__ int rI[4];
    if ((t & 63) == 0) { int wv = t >> 6; rm[wv] = m; rS[wv] = S; rW[wv] = W; rI[wv] = ix; }
    __syncthreads();
    if (t == 0) {
        float mm = rm[0], SS = rS[0], WW = rW[0];
        int II = rI[0];
#pragma unroll
        for (int wv = 1; wv < 4; ++wv) {
            float m2 = rm[wv], S2 = rS[wv], W2 = rW[wv];
            int i2 = rI[wv];
            float mx = fmaxf(mm, m2);
            float fa = __expf((mm - mx) * ITEMP);
            float fb = __expf((m2 - mx) * ITEMP);
            SS = SS * fa + S2 * fb;
            WW = WW * fa + W2 * fb;
            II = (m2 > mm || (m2 == mm && i2 < II)) ? i2 : II;
            mm = mx;
        }
        float best = WW / SS;
        int st = II >> 6, en = II & (NL - 1);
        int ks = en - st + 1 - MINWL;
        ks = ks < 0 ? 0 : (ks > NWL - 1 ? NWL - 1 : ks);
        int bv = mv[(b * NL + st) * NWL + ks];
        out[b] = (float)st;
        out[NB + b] = (float)en;
        out[2 * NB + b] = best;
        out[3 * NB + b] = (float)bv;
    }
}

extern "C" void kernel_launch(void* const* d_in, const int* in_sizes, int n_in,
                              void* d_out, int out_size, void* d_ws, size_t ws_size,
                              hipStream_t stream) {
    const float* word = (const float*)d_in[0];   // (B,L,D) f32
    const float* unit = (const float*)d_in[1];   // (U,D) f32
    const int* seg = (const int*)d_in[2];        // (V,MAXWL) i32
    const int* vlen = (const int*)d_in[3];       // (V,) i32
    float* out = (float*)d_out;                  // [start|end|score|vocab|dense]
    char* ws = (char*)d_ws;
    float* sim = (float*)ws;                     // 2,048,000 B
    int* mv = (int*)(ws + 2048000);              // 28,672 B
    int* origv = (int*)(ws + 2076672);           // 40,000 B
    int* segT = (int*)(ws + 2116672);            // 400,000 B
    int* bases = (int*)(ws + 2516672);           // 32 B
    float* dense = out + 4 * NB;

    hipFuncSetAttribute((const void*)k_sim,
                        hipFuncAttributeMaxDynamicSharedMemorySize, SIM_LDS_BYTES);

    k_sort<<<1, 512, 0, stream>>>(vlen, origv, bases);
    k_gather<<<(NV + 255) / 256, 256, 0, stream>>>(origv, seg, segT);
    k_sim<<<NB * 2 * 16, 256, SIM_LDS_BYTES, stream>>>(word, unit, sim);
    k_extract<<<NB * NL, NT, 0, stream>>>(sim, segT, origv, bases, dense, mv);
    k_final<<<NB, 256, 0, stream>>>(dense, mv, out);
}